// Round 7
// baseline (4220.456 us; speedup 1.0000x reference)
//
#include <hip/hip_runtime.h>
#include <math.h>

#define Bq 128
#define Tq 128
#define Vq 5000
#define VP 5120
#define Eq 256
#define Hq 512
#define Lq 128
#define G3H 1536
#define KT 128
#define LROW 136

typedef __attribute__((ext_vector_type(8))) short bf16x8;
typedef __attribute__((ext_vector_type(4))) float f32x4;

__device__ __forceinline__ ushort f2bf(float f) {
    union { float f; unsigned u; } v; v.f = f;
    unsigned r = (v.u + 0x7FFFu + ((v.u >> 16) & 1u)) >> 16;
    return (ushort)r;
}
__device__ __forceinline__ float bf2f(ushort s) {
    union { unsigned u; float f; } v; v.u = ((unsigned)s) << 16;
    return v.f;
}
__device__ __forceinline__ float lof(unsigned u) {
    union { unsigned x; float f; } v; v.x = u << 16; return v.f;
}
__device__ __forceinline__ float hif(unsigned u) {
    union { unsigned x; float f; } v; v.x = u & 0xFFFF0000u; return v.f;
}
__device__ __forceinline__ float rcpf(float x) { return __builtin_amdgcn_rcpf(x); }

// ---- MFMA tile accumulate, KT=128: acc += A[MI*32 x Klen] * B[128 x Klen]^T ----
template<int MI>
__device__ __forceinline__ void macT(
    f32x4 (&acc)[MI][4],
    const ushort* __restrict__ A, int lda,
    const ushort* __restrict__ Bm, int ldb,
    int n0, int kbase, int Klen,
    ushort* As, ushort* Bs)
{
    const int NA = 2 * MI;
    const int tid = threadIdx.x;
    const int lane = tid & 63;
    const int w = tid >> 6;
    const int wm = (w >> 1) * (MI * 16);
    const int wn = (w & 1) * 64;
    const int fr = lane & 15;
    const int fk = (lane >> 4) * 8;

    int arow[NA], akc[NA];
    #pragma unroll
    for (int i = 0; i < NA; ++i) {
        int c = tid + i * 256;
        arow[i] = c >> 4; akc[i] = (c & 15) * 8;
    }
    int brow[8], bkc[8];
    #pragma unroll
    for (int i = 0; i < 8; ++i) {
        int c = tid + i * 256;
        brow[i] = c >> 4; bkc[i] = (c & 15) * 8;
    }

    const int nk = Klen / KT;
    bf16x8 ra[NA], rb[8];
    #pragma unroll
    for (int i = 0; i < NA; ++i)
        ra[i] = *(const bf16x8*)(A + (size_t)arow[i] * lda + kbase + akc[i]);
    #pragma unroll
    for (int i = 0; i < 8; ++i)
        rb[i] = *(const bf16x8*)(Bm + (size_t)(n0 + brow[i]) * ldb + kbase + bkc[i]);
    #pragma unroll
    for (int i = 0; i < NA; ++i)
        *(bf16x8*)(As + arow[i] * LROW + akc[i]) = ra[i];
    #pragma unroll
    for (int i = 0; i < 8; ++i)
        *(bf16x8*)(Bs + brow[i] * LROW + bkc[i]) = rb[i];
    __syncthreads();

    for (int kt = 0; kt < nk; ++kt) {
        if (kt + 1 < nk) {
            int kb = kbase + (kt + 1) * KT;
            #pragma unroll
            for (int i = 0; i < NA; ++i)
                ra[i] = *(const bf16x8*)(A + (size_t)arow[i] * lda + kb + akc[i]);
            #pragma unroll
            for (int i = 0; i < 8; ++i)
                rb[i] = *(const bf16x8*)(Bm + (size_t)(n0 + brow[i]) * ldb + kb + bkc[i]);
        }
        #pragma unroll
        for (int ks = 0; ks < 4; ++ks) {
            bf16x8 af[MI], bfv[4];
            const int ko = ks * 32 + fk;
            #pragma unroll
            for (int mi = 0; mi < MI; ++mi)
                af[mi] = *(const bf16x8*)(As + (wm + mi * 16 + fr) * LROW + ko);
            #pragma unroll
            for (int ni = 0; ni < 4; ++ni)
                bfv[ni] = *(const bf16x8*)(Bs + (wn + ni * 16 + fr) * LROW + ko);
            #pragma unroll
            for (int mi = 0; mi < MI; ++mi)
                #pragma unroll
                for (int ni = 0; ni < 4; ++ni)
                    acc[mi][ni] = __builtin_amdgcn_mfma_f32_16x16x32_bf16(
                        af[mi], bfv[ni], acc[mi][ni], 0, 0, 0);
        }
        __syncthreads();
        if (kt + 1 < nk) {
            #pragma unroll
            for (int i = 0; i < NA; ++i)
                *(bf16x8*)(As + arow[i] * LROW + akc[i]) = ra[i];
            #pragma unroll
            for (int i = 0; i < 8; ++i)
                *(bf16x8*)(Bs + brow[i] * LROW + bkc[i]) = rb[i];
            __syncthreads();
        }
    }
}

// gh partial: j in [0,48): nt(12) x mh(2) x kc(2), MI=2
__device__ __forceinline__ void gh_block(
    int j, const ushort* __restrict__ hBsrc, const ushort* __restrict__ WhhB,
    ushort* __restrict__ ghp, ushort* As, ushort* Bs)
{
    const int tid = threadIdx.x;
    const int lane = tid & 63, w = tid >> 6;
    const int fr = lane & 15, hi = lane >> 4;
    const int nt = j >> 2, rem = j & 3;
    const int mh = rem >> 1, kc = rem & 1;
    const int n0 = nt * 128;
    const int wm = (w >> 1) * 32, wn = (w & 1) * 64;
    f32x4 acc[2][4];
    #pragma unroll
    for (int mi = 0; mi < 2; ++mi)
        #pragma unroll
        for (int ni = 0; ni < 4; ++ni) acc[mi][ni] = (f32x4){0.f,0.f,0.f,0.f};
    macT<2>(acc, hBsrc + (size_t)mh * 64 * Hq, Hq, WhhB, Hq,
            n0, kc * 256, 256, As, Bs);
    ushort* C = ghp + (size_t)kc * (Bq * G3H);
    #pragma unroll
    for (int mi = 0; mi < 2; ++mi)
        #pragma unroll
        for (int ni = 0; ni < 4; ++ni) {
            int n = n0 + wn + ni * 16 + fr;
            #pragma unroll
            for (int r = 0; r < 4; ++r) {
                int m = mh * 64 + wm + mi * 16 + hi * 4 + r;
                C[(size_t)m * G3H + n] = f2bf(acc[mi][ni][r]);
            }
        }
}

// normalize two output rows of step tprev, esl = esum slice (5120 floats)
__device__ __forceinline__ void norm2s(
    int bpair, int tprev, float* __restrict__ out,
    const float* __restrict__ esl)
{
    const int tid = threadIdx.x;
    #pragma unroll
    for (int j = 0; j < 2; ++j) {
        int b = bpair * 2 + j;
        float S = 0.f;
        #pragma unroll 8
        for (int nt = 0; nt < 40; ++nt)
            S += esl[nt * 128 + b];
        float inv = 1.0f / S;
        float* orow = out + ((size_t)b * Tq + tprev) * Vq;
        #pragma unroll
        for (int i = 0; i < 20; ++i) {
            int v = tid + i * 256;
            if (v < Vq) orow[v] *= inv;
        }
    }
}

// ================= K_Q: gates(t) (128 blk, 1 row each) + norm(t-1) (64 blk) ==
__global__ __launch_bounds__(256) void k_Q(
    const ushort* __restrict__ giP, const ushort* __restrict__ ghp,
    const float* __restrict__ b_ih, const float* __restrict__ b_hh,
    const float* __restrict__ h_old, const float* __restrict__ esumPrev,
    float* __restrict__ h_new, ushort* __restrict__ hB_new,
    float* __restrict__ out, int t)
{
    const int bid = blockIdx.x;
    const int tid = threadIdx.x;
    if (bid >= 128) {
        if (t > 0) norm2s(bid - 128, t - 1, out, esumPrev);
        return;
    }
    const int b = bid;
    float invS = 1.0f;
    if (t > 0) {
        float S = 0.f;
        #pragma unroll 8
        for (int q = 0; q < 40; ++q) S += esumPrev[q * 128 + b];
        invS = 1.0f / S;
    }
    const int i = tid * 2;                 // 0..510
    const size_t o = (size_t)b * G3H + i;
    float xr0=0.f,xr1=0.f,xz0=0.f,xz1=0.f,xn0=0.f,xn1=0.f;
    #pragma unroll 8
    for (int z = 0; z < 40; ++z) {
        const ushort* gp = giP + (size_t)z * (Bq * G3H) + o;
        unsigned ur = *(const unsigned*)(gp);
        unsigned uz = *(const unsigned*)(gp + Hq);
        unsigned un = *(const unsigned*)(gp + 2 * Hq);
        xr0 += lof(ur); xr1 += hif(ur);
        xz0 += lof(uz); xz1 += hif(uz);
        xn0 += lof(un); xn1 += hif(un);
    }
    float2 bir = *(const float2*)(b_ih + i);
    float2 biz = *(const float2*)(b_ih + Hq + i);
    float2 bin = *(const float2*)(b_ih + 2 * Hq + i);
    xr0 = xr0 * invS + bir.x;  xr1 = xr1 * invS + bir.y;
    xz0 = xz0 * invS + biz.x;  xz1 = xz1 * invS + biz.y;
    xn0 = xn0 * invS + bin.x;  xn1 = xn1 * invS + bin.y;
    const ushort* h0p = ghp + o;
    const ushort* h1p = ghp + (size_t)(Bq * G3H) + o;
    unsigned a0r = *(const unsigned*)(h0p);
    unsigned a0z = *(const unsigned*)(h0p + Hq);
    unsigned a0n = *(const unsigned*)(h0p + 2 * Hq);
    unsigned a1r = *(const unsigned*)(h1p);
    unsigned a1z = *(const unsigned*)(h1p + Hq);
    unsigned a1n = *(const unsigned*)(h1p + 2 * Hq);
    float2 bhr = *(const float2*)(b_hh + i);
    float2 bhz = *(const float2*)(b_hh + Hq + i);
    float2 bhn = *(const float2*)(b_hh + 2 * Hq + i);
    float hr0 = bhr.x + lof(a0r) + lof(a1r);
    float hr1 = bhr.y + hif(a0r) + hif(a1r);
    float hz0 = bhz.x + lof(a0z) + lof(a1z);
    float hz1 = bhz.y + hif(a0z) + hif(a1z);
    float hn0 = bhn.x + lof(a0n) + lof(a1n);
    float hn1 = bhn.y + hif(a0n) + hif(a1n);
    float r0 = rcpf(1.f + __expf(-(xr0 + hr0)));
    float r1 = rcpf(1.f + __expf(-(xr1 + hr1)));
    float z0 = rcpf(1.f + __expf(-(xz0 + hz0)));
    float z1 = rcpf(1.f + __expf(-(xz1 + hz1)));
    float e0 = __expf(2.f * (xn0 + r0 * hn0));
    float e1 = __expf(2.f * (xn1 + r1 * hn1));
    float nn0 = 1.f - 2.f * rcpf(e0 + 1.f);
    float nn1 = 1.f - 2.f * rcpf(e1 + 1.f);
    float2 ho = *(const float2*)(h_old + (size_t)b * Hq + i);
    float hv0 = (1.f - z0) * nn0 + z0 * ho.x;
    float hv1 = (1.f - z1) * nn1 + z1 * ho.y;
    *(float2*)(h_new + (size_t)b * Hq + i) = make_float2(hv0, hv1);
    unsigned hb = (unsigned)f2bf(hv0) | ((unsigned)f2bf(hv1) << 16);
    *(unsigned*)(hB_new + (size_t)b * Hq + i) = hb;
}

// ================= K_P: logits(t) + gi(t+1) partial (160 blk) + gh(t+1) (48) =
// Same dataflow/indexing as round-6 K_P; rebuilt with double-buffered LDS
// (1 barrier per K-chunk) and coalesced giP stores via transpose slabs.
__global__ __launch_bounds__(256) void k_P(
    const ushort* __restrict__ hBt, const ushort* __restrict__ WoutB,
    const ushort* __restrict__ WhhB, const ushort* __restrict__ WcombT,
    const float* __restrict__ b_out, const float* __restrict__ gum,
    const float* __restrict__ temp, float* __restrict__ out,
    float* __restrict__ esumCur, ushort* __restrict__ giP,
    ushort* __restrict__ ghp, int t)
{
    __shared__ __align__(16) ushort As[64 * LROW];     // logits A dbuf halves / yt tile (rows 0..31)
    __shared__ __align__(16) ushort Bs[2][128 * LROW]; // B-operand double buffer
    __shared__ __align__(16) ushort Xs[2][32 * LROW];  // giP transpose slabs / redbuf
    const int tid = threadIdx.x, bid = blockIdx.x;
    const int lane = tid & 63, w = tid >> 6;
    const int fr = lane & 15, hi = lane >> 4, fk = hi * 8;

    if (bid >= 160) {
        if (t + 1 < Tq)
            gh_block(bid - 160, hBt, WhhB, ghp, As, Bs[0]);
        return;
    }
    const int nt = bid % 40, mq = bid / 40;
    const int b0 = mq * 32, ncol0 = nt * 128;
    const int wm = (w >> 1) * 16, wn = (w & 1) * 64;

    int arow[2], akc[2], brow[8], bkc[8];
    #pragma unroll
    for (int i = 0; i < 2; ++i) { int c = tid + i * 256; arow[i] = c >> 4; akc[i] = (c & 15) * 8; }
    #pragma unroll
    for (int i = 0; i < 8; ++i) { int c = tid + i * 256; brow[i] = c >> 4; bkc[i] = (c & 15) * 8; }

    // ---------- logits GEMM: C[32x128] = hB[32x512] * WoutB[128x512]^T ------
    const ushort* Abase = hBt + (size_t)b0 * Hq;
    const ushort* Bbase = WoutB + (size_t)ncol0 * Hq;
    bf16x8 ra[2], rb[8];
    #pragma unroll
    for (int i = 0; i < 2; ++i)
        ra[i] = *(const bf16x8*)(Abase + (size_t)arow[i] * Hq + akc[i]);
    #pragma unroll
    for (int i = 0; i < 8; ++i)
        rb[i] = *(const bf16x8*)(Bbase + (size_t)brow[i] * Hq + bkc[i]);
    #pragma unroll
    for (int i = 0; i < 2; ++i)
        *(bf16x8*)(As + arow[i] * LROW + akc[i]) = ra[i];
    #pragma unroll
    for (int i = 0; i < 8; ++i)
        *(bf16x8*)(Bs[0] + brow[i] * LROW + bkc[i]) = rb[i];
    __syncthreads();

    f32x4 acc[4];
    #pragma unroll
    for (int ni = 0; ni < 4; ++ni) acc[ni] = (f32x4){0.f,0.f,0.f,0.f};
    int cur = 0;
    for (int kt = 0; kt < 4; ++kt) {
        if (kt < 3) {
            const int kb = (kt + 1) * KT;
            #pragma unroll
            for (int i = 0; i < 2; ++i)
                ra[i] = *(const bf16x8*)(Abase + (size_t)arow[i] * Hq + kb + akc[i]);
            #pragma unroll
            for (int i = 0; i < 8; ++i)
                rb[i] = *(const bf16x8*)(Bbase + (size_t)brow[i] * Hq + kb + bkc[i]);
        }
        #pragma unroll
        for (int ks = 0; ks < 4; ++ks) {
            const int ko = ks * 32 + fk;
            bf16x8 af = *(const bf16x8*)(As + (cur * 32 + wm + fr) * LROW + ko);
            #pragma unroll
            for (int ni = 0; ni < 4; ++ni) {
                bf16x8 bfv = *(const bf16x8*)(Bs[cur] + (wn + ni * 16 + fr) * LROW + ko);
                acc[ni] = __builtin_amdgcn_mfma_f32_16x16x32_bf16(af, bfv, acc[ni], 0, 0, 0);
            }
        }
        if (kt < 3) {
            const int alt = cur ^ 1;
            #pragma unroll
            for (int i = 0; i < 2; ++i)
                *(bf16x8*)(As + (alt * 32 + arow[i]) * LROW + akc[i]) = ra[i];
            #pragma unroll
            for (int i = 0; i < 8; ++i)
                *(bf16x8*)(Bs[alt] + brow[i] * LROW + bkc[i]) = rb[i];
            __syncthreads();
            cur = alt;
        }
    }
    // final kt read As rows 32..63 + Bs[1]; yt goes to As rows 0..31 (disjoint)

    // ---------- epilogue: gumbel+exp -> out(unnorm), yt->As, esum ----------
    const float inv_tau = 1.0f / temp[0];
    float psum[4] = {0.f, 0.f, 0.f, 0.f};
    #pragma unroll
    for (int ni = 0; ni < 4; ++ni) {
        int v = ncol0 + wn + ni * 16 + fr;
        bool valid = v < Vq;
        float bo = valid ? b_out[v] : 0.f;
        #pragma unroll
        for (int r = 0; r < 4; ++r) {
            int ml = wm + hi * 4 + r;
            int m = b0 + ml;
            float ev = 0.f;
            if (valid) {
                float g = gum[(size_t)m * Vq + v];
                ev = __expf((acc[ni][r] + bo + g) * inv_tau);
                out[(size_t)m * Tq * Vq + (size_t)t * Vq + v] = ev;
            }
            As[ml * LROW + (wn + ni * 16 + fr)] = f2bf(ev);   // yt tile
            psum[r] += ev;
        }
    }
    float* redbuf = (float*)Xs[0];
    #pragma unroll
    for (int r = 0; r < 4; ++r) {
        float s = psum[r];
        s += __shfl_xor(s, 1); s += __shfl_xor(s, 2);
        s += __shfl_xor(s, 4); s += __shfl_xor(s, 8);
        if (fr == 0)
            redbuf[((wm + hi * 4 + r) << 1) | (wn >> 6)] = s;
    }
    __syncthreads();
    if (tid < 32)
        esumCur[ncol0 + b0 + tid] = redbuf[tid * 2] + redbuf[tid * 2 + 1];

    // ---------- gi(t+1) partial: P[32x1536] = yt[32x128] * WcombT^T ---------
    if (t + 1 >= Tq) return;
    #pragma unroll
    for (int i = 0; i < 8; ++i)
        rb[i] = *(const bf16x8*)(WcombT + (size_t)brow[i] * VP + ncol0 + bkc[i]);
    #pragma unroll
    for (int i = 0; i < 8; ++i)
        *(bf16x8*)(Bs[0] + brow[i] * LROW + bkc[i]) = rb[i];
    __syncthreads();

    ushort* Pbase = giP + (size_t)nt * (Bq * G3H) + (size_t)b0 * G3H;
    int bcur = 0;
    for (int jt = 0; jt < 12; ++jt) {
        if (jt + 1 < 12) {
            #pragma unroll
            for (int i = 0; i < 8; ++i)
                rb[i] = *(const bf16x8*)(WcombT +
                    (size_t)((jt + 1) * 128 + brow[i]) * VP + ncol0 + bkc[i]);
        }
        // drain previous slab to global (coalesced bf16x8 stores)
        if (jt > 0) {
            const ushort* Xp = Xs[(jt - 1) & 1];
            ushort* Pp = Pbase + (size_t)(jt - 1) * 128;
            #pragma unroll
            for (int q = 0; q < 2; ++q) {
                int vv = tid + q * 256;
                int r = vv >> 4, c8 = (vv & 15) * 8;
                *(bf16x8*)(Pp + (size_t)r * G3H + c8) =
                    *(const bf16x8*)(Xp + r * LROW + c8);
            }
        }
        // MFMA on Bs[bcur], A = yt (static in As rows 0..31)
        f32x4 pac[4];
        #pragma unroll
        for (int ni = 0; ni < 4; ++ni) pac[ni] = (f32x4){0.f,0.f,0.f,0.f};
        #pragma unroll
        for (int ks = 0; ks < 4; ++ks) {
            const int ko = ks * 32 + fk;
            bf16x8 af = *(const bf16x8*)(As + (wm + fr) * LROW + ko);
            #pragma unroll
            for (int ni = 0; ni < 4; ++ni) {
                bf16x8 bv = *(const bf16x8*)(Bs[bcur] + (wn + ni * 16 + fr) * LROW + ko);
                pac[ni] = __builtin_amdgcn_mfma_f32_16x16x32_bf16(af, bv, pac[ni], 0, 0, 0);
            }
        }
        // scatter to slab jt&1 (LDS; drained next iteration)
        ushort* Xc = Xs[jt & 1];
        #pragma unroll
        for (int ni = 0; ni < 4; ++ni) {
            int jl = wn + ni * 16 + fr;
            #pragma unroll
            for (int r = 0; r < 4; ++r)
                Xc[(wm + hi * 4 + r) * LROW + jl] = f2bf(pac[ni][r]);
        }
        if (jt + 1 < 12) {
            #pragma unroll
            for (int i = 0; i < 8; ++i)
                *(bf16x8*)(Bs[bcur ^ 1] + brow[i] * LROW + bkc[i]) = rb[i];
        }
        __syncthreads();
        bcur ^= 1;
    }
    {   // final drain (jt = 11 slab)
        const ushort* Xp = Xs[1];
        ushort* Pp = Pbase + (size_t)11 * 128;
        #pragma unroll
        for (int q = 0; q < 2; ++q) {
            int vv = tid + q * 256;
            int r = vv >> 4, c8 = (vv & 15) * 8;
            *(bf16x8*)(Pp + (size_t)r * G3H + c8) = *(const bf16x8*)(Xp + r * LROW + c8);
        }
    }
}

// ================= prep / wh0 / gh0+zero / tail ==============================
__global__ __launch_bounds__(256) void k_prep(
    const float* __restrict__ W_ih, const float* __restrict__ W_hh,
    const float* __restrict__ W_out, const float* __restrict__ noise,
    const float* __restrict__ W_init, const float* __restrict__ emb,
    ushort* __restrict__ WihB, ushort* __restrict__ WhhB, ushort* __restrict__ WoutB,
    ushort* __restrict__ noiseB, ushort* __restrict__ WinitB,
    ushort* __restrict__ embB)
{
    const int tg = blockIdx.x * 256 + threadIdx.x;
    const int NTH = gridDim.x * 256;
    for (int i = tg; i < G3H * Eq / 4; i += NTH) {
        float4 f = *(const float4*)(W_ih + (size_t)i * 4);
        *(ushort4*)(WihB + (size_t)i * 4) =
            make_ushort4(f2bf(f.x), f2bf(f.y), f2bf(f.z), f2bf(f.w));
    }
    for (int i = tg; i < G3H * Hq / 4; i += NTH) {
        float4 f = *(const float4*)(W_hh + (size_t)i * 4);
        *(ushort4*)(WhhB + (size_t)i * 4) =
            make_ushort4(f2bf(f.x), f2bf(f.y), f2bf(f.z), f2bf(f.w));
    }
    for (int i = tg; i < VP * (Hq / 4); i += NTH) {
        int v = i >> 7, h4 = (i & 127) << 2;
        ushort4 o = make_ushort4(0, 0, 0, 0);
        if (v < Vq) {
            float4 f = *(const float4*)(W_out + (size_t)v * Hq + h4);
            o = make_ushort4(f2bf(f.x), f2bf(f.y), f2bf(f.z), f2bf(f.w));
        }
        *(ushort4*)(WoutB + (size_t)v * Hq + h4) = o;
    }
    for (int i = tg; i < VP * (Eq / 4); i += NTH) {
        int v = i >> 6, e4 = (i & 63) << 2;
        ushort4 o = make_ushort4(0, 0, 0, 0);
        if (v < Vq) {
            float4 f = *(const float4*)(emb + (size_t)v * Eq + e4);
            o = make_ushort4(f2bf(f.x), f2bf(f.y), f2bf(f.z), f2bf(f.w));
        }
        *(ushort4*)(embB + (size_t)v * Eq + e4) = o;
    }
    for (int i = tg; i < Bq * Lq / 4; i += NTH) {
        float4 f = *(const float4*)(noise + (size_t)i * 4);
        *(ushort4*)(noiseB + (size_t)i * 4) =
            make_ushort4(f2bf(f.x), f2bf(f.y), f2bf(f.z), f2bf(f.w));
    }
    for (int i = tg; i < Hq * Lq / 4; i += NTH) {
        float4 f = *(const float4*)(W_init + (size_t)i * 4);
        *(ushort4*)(WinitB + (size_t)i * 4) =
            make_ushort4(f2bf(f.x), f2bf(f.y), f2bf(f.z), f2bf(f.w));
    }
}

__global__ __launch_bounds__(256) void k_wh0(
    const ushort* __restrict__ WihB, const ushort* __restrict__ embB,
    const ushort* __restrict__ noiseB, const ushort* __restrict__ WinitB,
    const float* __restrict__ b_init,
    ushort* __restrict__ WcombT, float* __restrict__ h0, ushort* __restrict__ hB0)
{
    __shared__ __align__(16) ushort As[128 * LROW];
    __shared__ __align__(16) ushort Bs[128 * LROW];
    const int bid = blockIdx.x;
    const int lane = threadIdx.x & 63;
    const int w = threadIdx.x >> 6;
    const int wm = (w >> 1) * 64, wn = (w & 1) * 64;
    const int fr = lane & 15, hi = lane >> 4;
    f32x4 acc[4][4];
    #pragma unroll
    for (int mi = 0; mi < 4; ++mi)
        #pragma unroll
        for (int ni = 0; ni < 4; ++ni) acc[mi][ni] = (f32x4){0.f,0.f,0.f,0.f};
    if (bid < 480) {
        int mt = bid / 40, nt = bid % 40;
        macT<4>(acc, WihB + (size_t)mt * 128 * Eq, Eq, embB, Eq,
                nt * 128, 0, Eq, As, Bs);
        #pragma unroll
        for (int mi = 0; mi < 4; ++mi)
            #pragma unroll
            for (int ni = 0; ni < 4; ++ni) {
                int n = nt * 128 + wn + ni * 16 + fr;
                #pragma unroll
                for (int r = 0; r < 4; ++r) {
                    int m = mt * 128 + wm + mi * 16 + hi * 4 + r;
                    WcombT[(size_t)m * VP + n] = f2bf(acc[mi][ni][r]);
                }
            }
    } else {
        int n0 = (bid - 480) * 128;
        macT<4>(acc, noiseB, Lq, WinitB, Lq, n0, 0, Lq, As, Bs);
        #pragma unroll
        for (int mi = 0; mi < 4; ++mi)
            #pragma unroll
            for (int ni = 0; ni < 4; ++ni) {
                int n = n0 + wn + ni * 16 + fr;
                float bv = b_init[n];
                #pragma unroll
                for (int r = 0; r < 4; ++r) {
                    int m = wm + mi * 16 + hi * 4 + r;
                    float v = acc[mi][ni][r] + bv;
                    h0[(size_t)m * Hq + n] = v;
                    hB0[(size_t)m * Hq + n] = f2bf(v);
                }
            }
    }
}

// gh(0) (48 blk) + zero giP (192 blk). Runs after k_wh0 (embB etc. dead).
__global__ __launch_bounds__(256) void k_gh0(
    const ushort* __restrict__ hB0, const ushort* __restrict__ WhhB,
    ushort* __restrict__ ghp, ushort* __restrict__ giP)
{
    __shared__ __align__(16) ushort As[64 * LROW];
    __shared__ __align__(16) ushort Bs[128 * LROW];
    const int bid = blockIdx.x;
    if (bid < 48) {
        gh_block(bid, hB0, WhhB, ghp, As, Bs);
    } else {
        const int zb = bid - 48;                 // 0..191
        ushort4* p = (ushort4*)giP;
        const int total = 40 * Bq * G3H / 4;     // 1,966,080 ushort4
        const int per = total / 192;             // 10240
        int base = zb * per + threadIdx.x;
        #pragma unroll 8
        for (int k = 0; k < 40; ++k)
            p[base + k * 256] = make_ushort4(0, 0, 0, 0);
    }
}

__global__ __launch_bounds__(256) void k_tail(
    float* __restrict__ out, const float* __restrict__ esl)
{
    norm2s(blockIdx.x, Tq - 1, out, esl);
}

// ================= host ======================================================
extern "C" void kernel_launch(void* const* d_in, const int* in_sizes, int n_in,
                              void* d_out, int out_size, void* d_ws, size_t ws_size,
                              hipStream_t stream)
{
    const float* noise   = (const float*)d_in[0];
    const float* gumbel  = (const float*)d_in[1];
    const float* temp    = (const float*)d_in[2];
    const float* W_init  = (const float*)d_in[3];
    const float* b_init  = (const float*)d_in[4];
    const float* emb     = (const float*)d_in[5];
    const float* W_ih    = (const float*)d_in[6];
    const float* W_hh    = (const float*)d_in[7];
    const float* b_ih    = (const float*)d_in[8];
    const float* b_hh    = (const float*)d_in[9];
    const float* W_out   = (const float*)d_in[10];
    const float* b_out   = (const float*)d_in[11];
    float* out = (float*)d_out;

    // ---- workspace layout (~39.9 MB) ----
    float* h       = (float*)d_ws;                // 2 x 65536 f32 (ping-pong)
    float* esum    = h + 131072;                  // 2 x 5120 f32 (ping-pong)
    ushort* ub     = (ushort*)(esum + 10240);
    ushort* ghp    = ub;                          // 393216
    ushort* WhhB   = ghp + 393216;                // 786432
    ushort* WoutB  = WhhB + 786432;               // 2621440
    ushort* WcombT = WoutB + 2621440;             // 7864320
    ushort* hB     = WcombT + 7864320;            // 2 x 65536
    ushort* giP    = hB + 131072;                 // 40 x 196608 = 7864320
    // init-only buffers overlaid on giP (dead after k_wh0; giP zeroed by k_gh0)
    ushort* embB   = giP;                         // 1310720
    ushort* WihB   = embB + 1310720;              // 393216
    ushort* noiseB = WihB + 393216;               // 16384
    ushort* WinitB = noiseB + 16384;              // 65536

    k_prep<<<dim3(512), dim3(256), 0, stream>>>(
        W_ih, W_hh, W_out, noise, W_init, emb,
        WihB, WhhB, WoutB, noiseB, WinitB, embB);
    k_wh0<<<dim3(484), dim3(256), 0, stream>>>(
        WihB, embB, noiseB, WinitB, b_init, WcombT, h, hB);
    k_gh0<<<dim3(240), dim3(256), 0, stream>>>(hB, WhhB, ghp, giP);

    for (int t = 0; t < Tq; ++t) {
        float* h_old = h + (size_t)(t & 1) * 65536;
        float* h_new = h + (size_t)((t + 1) & 1) * 65536;
        ushort* hB_new = hB + (size_t)((t + 1) & 1) * 65536;
        float* esumPrev = esum + (size_t)((t + 1) & 1) * 5120;  // slice (t-1)&1
        float* esumCur  = esum + (size_t)(t & 1) * 5120;

        k_Q<<<dim3(192), dim3(256), 0, stream>>>(
            giP, ghp, b_ih, b_hh, h_old, esumPrev, h_new, hB_new, out, t);
        k_P<<<dim3(t + 1 < Tq ? 208 : 160), dim3(256), 0, stream>>>(
            hB_new, WoutB, WhhB, WcombT, b_out,
            gumbel + (size_t)t * Bq * Vq, temp,
            out, esumCur, giP, ghp, t);
    }
    k_tail<<<dim3(64), dim3(256), 0, stream>>>(
        out, esum + (size_t)((Tq - 1) & 1) * 5120);
}